// Round 7
// baseline (257.866 us; speedup 1.0000x reference)
//
#include <hip/hip_runtime.h>
#include <stdint.h>

// Problem constants
constexpr int C_IN  = 512;
constexpr int HW    = 784;            // 28*28
constexpr int NB    = 32;
constexpr int M_TOT = NB * HW;        // 25088
constexpr int N_TOT = 2000;
constexpr int NPAD  = 2048;
constexpr int IMG_STRIDE = C_IN * HW;
constexpr int OUT_BATCH  = N_TOT * HW;

// GEMM tiling: 128x128, BK=32, 16 K-tiles, ring-2 LDS (32 KB), 5 blocks/CU
constexpr int TBM = 128;
constexpr int TBN = 128;
constexpr int NKT = C_IN / 32;        // 16

constexpr int PREPA_BLOCKS = M_TOT / 64;   // 392
constexpr int PREPW_BLOCKS = NPAD / 4;     // 512

typedef __attribute__((ext_vector_type(8))) short bf16x8;
typedef __attribute__((ext_vector_type(4))) float f32x4;

__device__ __forceinline__ uint16_t f2bf(float f) {
    union { float f; uint32_t u; } x; x.f = f;
    return (uint16_t)((x.u + 0x8000u) >> 16);
}

__device__ __forceinline__ void gload_lds16(const void* g, void* l) {
    __builtin_amdgcn_global_load_lds(
        (const __attribute__((address_space(1))) void*)g,
        (__attribute__((address_space(3))) void*)l, 16, 0, 0);
}

// ---------------------------------------------------------------------------
// prep: blocks [0,392): Abf[m][k] = bf16(input) transposed via LDS, fused s2[m]
//       blocks [392,904): Wbf[p][k] = bf16(w) (rows >= N_TOT zeroed), fused w2[p]
__global__ __launch_bounds__(256) void prep_kernel(const float* __restrict__ in,
                                                   const float* __restrict__ w,
                                                   short* __restrict__ Abf,
                                                   short* __restrict__ Wbf,
                                                   float* __restrict__ s2,
                                                   float* __restrict__ w2) {
    __shared__ __align__(16) char T[64 * 512 * 2];
    __shared__ float red[16][64];

    const int t = threadIdx.x;

    if (blockIdx.x >= PREPA_BLOCKS) {
        // ---- prep_w body: wave per row
        const int wv = t >> 6, lane = t & 63;
        const int p = (blockIdx.x - PREPA_BLOCKS) * 4 + wv;
        bf16x8 o = (bf16x8)0;
        float s = 0.f;
        if (p < N_TOT) {
            const float* base = w + (size_t)p * C_IN + lane * 8;
            float4 a = *(const float4*)base;
            float4 c = *(const float4*)(base + 4);
            s = a.x*a.x + a.y*a.y + a.z*a.z + a.w*a.w
              + c.x*c.x + c.y*c.y + c.z*c.z + c.w*c.w;
            o[0] = (short)f2bf(a.x); o[1] = (short)f2bf(a.y);
            o[2] = (short)f2bf(a.z); o[3] = (short)f2bf(a.w);
            o[4] = (short)f2bf(c.x); o[5] = (short)f2bf(c.y);
            o[6] = (short)f2bf(c.z); o[7] = (short)f2bf(c.w);
        }
        *(bf16x8*)(Wbf + (size_t)p * C_IN + lane * 8) = o;
#pragma unroll
        for (int off = 32; off; off >>= 1) s += __shfl_down(s, off);
        if (lane == 0) w2[p] = s;
        return;
    }

    // ---- prep_a body
    const int q = t & 15;
    const int part = t >> 4;
    const int m0q = blockIdx.x * 64 + q * 4;
    const uint32_t b  = (uint32_t)m0q / 784u;
    const uint32_t hw = (uint32_t)m0q % 784u;
    const float* base = in + (size_t)b * IMG_STRIDE + hw;

    float4 acc = make_float4(0.f, 0.f, 0.f, 0.f);
    const int c0 = part * 32;
#pragma unroll 4
    for (int c = c0; c < c0 + 32; ++c) {
        float4 v = *(const float4*)(base + (size_t)c * HW);
        acc.x = fmaf(v.x, v.x, acc.x);
        acc.y = fmaf(v.y, v.y, acc.y);
        acc.z = fmaf(v.z, v.z, acc.z);
        acc.w = fmaf(v.w, v.w, acc.w);
        uint16_t vals[4] = { f2bf(v.x), f2bf(v.y), f2bf(v.z), f2bf(v.w) };
        const uint32_t by0 = (uint32_t)(q * 4) * 1024u + (uint32_t)c * 2u;
#pragma unroll
        for (int j = 0; j < 4; ++j) {
            uint32_t bb = by0 + (uint32_t)j * 1024u;
            bb ^= ((bb >> 12) & 7u) << 4;
            *(uint16_t*)(T + bb) = vals[j];
        }
    }
    red[part][q * 4 + 0] = acc.x;
    red[part][q * 4 + 1] = acc.y;
    red[part][q * 4 + 2] = acc.z;
    red[part][q * 4 + 3] = acc.w;
    __syncthreads();
    if (t < 64) {
        float s = 0.f;
#pragma unroll
        for (int p = 0; p < 16; ++p) s += red[p][t];
        s2[blockIdx.x * 64 + t] = s;
    }
    short* dst = Abf + (size_t)blockIdx.x * 64 * 512;
#pragma unroll
    for (int i = 0; i < 16; ++i) {
        const int idx = i * 256 + t;
        const int row = idx >> 6, ch = idx & 63;
        uint32_t bb = (uint32_t)row * 1024u + (uint32_t)ch * 16u;
        bb ^= ((bb >> 12) & 7u) << 4;
        bf16x8 v = *(bf16x8*)(T + bb);
        *(bf16x8*)(dst + (size_t)row * 512 + ch * 8) = v;
    }
}

// ---------------------------------------------------------------------------
// gemm7: 128x128 tile, BK=32, ring-2 LDS (2 x 16 KB = 32 KB -> 5 blocks/CU),
// T3 minimum-2-phase: STAGE(kt+1) issued BEFORE compute(kt); one
// lgkmcnt(0)+vmcnt(0)+barrier per K-tile (stage has a full compute of cover).
// Conflict-free slot swizzle (linear LDS dest + pre-swizzled global source,
// bank-conflict == 0 measured). Fused relu(s2 - 2*acc + w2) epilogue.
//
// LDS buffer (16 KB): A 128 rows x 32k bf16 (64 B/row) at +0, B at +8192.
// Storage slot s of row r holds logical k-group s ^ ((r>>1)&3).
__global__ __launch_bounds__(256, 5) void gemm7_kernel(const short* __restrict__ Abf,
                                                       const short* __restrict__ Wbf,
                                                       const float* __restrict__ s2,
                                                       const float* __restrict__ w2,
                                                       float* __restrict__ out) {
    __shared__ __align__(16) char smem[32768];    // 2 bufs x 16 KB

    const int t = threadIdx.x;
    const int wv = t >> 6, lane = t & 63;
    const int lr = lane & 15, lg = lane >> 4;

    const int bid = blockIdx.x;
    const int bn = bid & 15;               // fast: 16 blocks share one A panel
    const int bm = bid >> 4;

    const short* Ab = Abf + (size_t)bm * TBM * C_IN;
    const short* Bb = Wbf + (size_t)bn * TBN * C_IN;

    // ---- staging: wave wv, instr j: dest byte = j*1024 + wv*2048?  (see below)
    //      dest = adst + j*1024 + lane*16 -> row = (adst+j*1024)/64 + (lane>>2),
    //      storage slot = lane&3. Source logical k-group = (lane&3)^((lane>>3)&3).
    const int srow = wv * 32 + (lane >> 2);
    const int sg   = (lane & 3) ^ ((lane >> 3) & 3);
    const short* AsrcL = Ab + (size_t)srow * C_IN + sg * 8;
    const short* BsrcL = Bb + (size_t)srow * C_IN + sg * 8;
    const int adst = wv * 2048;            // wave covers rows wv*32 (j=0) / +16 (j=1)

    // ---- wave -> output subtile (64m x 64n)
    const int wm = (wv >> 1) * 64;         // {0,64}
    const int wn = (wv & 1) * 64;          // {0,64}

    // ---- ds_read offsets: row r, slot lg^((lr>>1)&3); frag stride 1024 B
    const int slot  = lg ^ ((lr >> 1) & 3);
    const int abase = (wm + lr) * 64 + slot * 16;
    const int bbase = 8192 + (wn + lr) * 64 + slot * 16;

    f32x4 acc[4][4] = {};

#define STAGE(tt)                                                              \
    do {                                                                       \
        char* buf_ = smem + ((tt) & 1) * 16384;                                \
        const short* As_ = AsrcL + (tt) * 32;                                  \
        const short* Bs_ = BsrcL + (tt) * 32;                                  \
        gload_lds16(As_,             buf_ + adst);                             \
        gload_lds16(As_ + 16 * 512,  buf_ + adst + 1024);                      \
        gload_lds16(Bs_,             buf_ + 8192 + adst);                      \
        gload_lds16(Bs_ + 16 * 512,  buf_ + 8192 + adst + 1024);               \
    } while (0)

    // prologue: stage tile 0, drain, sync
    STAGE(0);
    asm volatile("s_waitcnt vmcnt(0)" ::: "memory");
    __builtin_amdgcn_sched_barrier(0);
    __builtin_amdgcn_s_barrier();
    __builtin_amdgcn_sched_barrier(0);

#pragma unroll
    for (int kt = 0; kt < NKT; ++kt) {
        // issue next tile's stage FIRST (into buf^1, freed at the last barrier)
        if (kt + 1 < NKT) STAGE(kt + 1);

        const char* buf = smem + (kt & 1) * 16384;
        bf16x8 bfrag[4], afrag[4];
#pragma unroll
        for (int n = 0; n < 4; ++n)
            bfrag[n] = *(const bf16x8*)(buf + bbase + n * 1024);
#pragma unroll
        for (int m = 0; m < 4; ++m)
            afrag[m] = *(const bf16x8*)(buf + abase + m * 1024);

        __builtin_amdgcn_s_setprio(1);
#pragma unroll
        for (int m = 0; m < 4; ++m)
#pragma unroll
            for (int n = 0; n < 4; ++n)
                acc[m][n] = __builtin_amdgcn_mfma_f32_16x16x32_bf16(
                    afrag[m], bfrag[n], acc[m][n], 0, 0, 0);
        __builtin_amdgcn_s_setprio(0);

        if (kt + 1 < NKT) {
            // my ds_reads of buf done (MFMA deps already forced it) + my
            // stage(kt+1) landed; barrier makes both true for ALL waves.
            asm volatile("s_waitcnt vmcnt(0) lgkmcnt(0)" ::: "memory");
            __builtin_amdgcn_sched_barrier(0);
            __builtin_amdgcn_s_barrier();
            __builtin_amdgcn_sched_barrier(0);
        }
    }
#undef STAGE

    // epilogue: relu(s2 - 2*acc + w2), float4 over 4 consecutive m (hw-contig)
#pragma unroll
    for (int m = 0; m < 4; ++m) {
        const int m_r = bm * TBM + wm + m * 16 + lg * 4;   // 4-aligned, 784%4==0
        const float4 s2v = *(const float4*)(s2 + m_r);
        const uint32_t ob  = (uint32_t)m_r / 784u;
        const uint32_t ohw = (uint32_t)m_r % 784u;
        float* obase = out + (size_t)ob * OUT_BATCH + ohw;
#pragma unroll
        for (int n = 0; n < 4; ++n) {
            const int n_o = bn * TBN + wn + n * 16 + lr;
            if (n_o < N_TOT) {
                const float wvv = w2[n_o];
                const f32x4 a = acc[m][n];
                float4 r;
                r.x = fmaxf(s2v.x - 2.f * a.x + wvv, 0.f);
                r.y = fmaxf(s2v.y - 2.f * a.y + wvv, 0.f);
                r.z = fmaxf(s2v.z - 2.f * a.z + wvv, 0.f);
                r.w = fmaxf(s2v.w - 2.f * a.w + wvv, 0.f);
                *(float4*)(obase + (size_t)n_o * HW) = r;
            }
        }
    }
}

// ---------------------------------------------------------------------------
extern "C" void kernel_launch(void* const* d_in, const int* in_sizes, int n_in,
                              void* d_out, int out_size, void* d_ws, size_t ws_size,
                              hipStream_t stream) {
    const float* in = (const float*)d_in[0];   // [32,512,28,28] fp32
    const float* w  = (const float*)d_in[1];   // [2000,512,1,1] fp32
    float* out = (float*)d_out;                // [32,2000,28,28] fp32

    const size_t offA  = 0;
    const size_t offW  = offA + (size_t)M_TOT * C_IN * sizeof(short);   // 25.7 MB
    const size_t offS2 = offW + (size_t)NPAD * C_IN * sizeof(short);    // +2.1 MB
    const size_t offW2 = offS2 + (size_t)M_TOT * sizeof(float);

    short* Abf = (short*)((char*)d_ws + offA);
    short* Wbf = (short*)((char*)d_ws + offW);
    float* s2  = (float*)((char*)d_ws + offS2);
    float* w2  = (float*)((char*)d_ws + offW2);

    prep_kernel<<<PREPA_BLOCKS + PREPW_BLOCKS, 256, 0, stream>>>(in, w, Abf, Wbf, s2, w2);

    // 196 m-tiles x 16 n-tiles = 3136 blocks, 5 resident per CU
    gemm7_kernel<<<196 * 16, 256, 0, stream>>>(Abf, Wbf, s2, w2, out);
}

// Round 8
// 123.161 us; speedup vs baseline: 2.0937x; 2.0937x over previous
//
#include <hip/hip_runtime.h>
#include <stdint.h>

// Problem constants
constexpr int C_IN  = 512;
constexpr int HW    = 784;            // 28*28
constexpr int NB    = 32;
constexpr int M_TOT = NB * HW;        // 25088 = 98*256
constexpr int N_TOT = 2000;
constexpr int NPAD  = 2048;
constexpr int IMG_STRIDE = C_IN * HW;
constexpr int OUT_BATCH  = N_TOT * HW;

// GEMM tiling: 256x128, BK=64, 8 K-tiles, ring-3 LDS (144 KB), 8 waves
constexpr int TBM = 256;
constexpr int TBN = 128;
constexpr int NKT = C_IN / 64;        // 8

constexpr int PREPA_BLOCKS = M_TOT / 64;   // 392
constexpr int PREPW_BLOCKS = NPAD / 4;     // 512

typedef __attribute__((ext_vector_type(8))) short bf16x8;
typedef __attribute__((ext_vector_type(4))) float f32x4;

__device__ __forceinline__ uint16_t f2bf(float f) {
    union { float f; uint32_t u; } x; x.f = f;
    return (uint16_t)((x.u + 0x8000u) >> 16);
}

__device__ __forceinline__ void gload_lds16(const void* g, void* l) {
    __builtin_amdgcn_global_load_lds(
        (const __attribute__((address_space(1))) void*)g,
        (__attribute__((address_space(3))) void*)l, 16, 0, 0);
}

// ---------------------------------------------------------------------------
// prep: blocks [0,392): Abf[m][k] = bf16(input) transposed via LDS, fused s2[m]
//       blocks [392,904): Wbf[p][k] = bf16(w) (rows >= N_TOT zeroed), fused w2[p]
__global__ __launch_bounds__(256) void prep_kernel(const float* __restrict__ in,
                                                   const float* __restrict__ w,
                                                   short* __restrict__ Abf,
                                                   short* __restrict__ Wbf,
                                                   float* __restrict__ s2,
                                                   float* __restrict__ w2) {
    __shared__ __align__(16) char T[64 * 512 * 2];
    __shared__ float red[16][64];

    const int t = threadIdx.x;

    if (blockIdx.x >= PREPA_BLOCKS) {
        const int wv = t >> 6, lane = t & 63;
        const int p = (blockIdx.x - PREPA_BLOCKS) * 4 + wv;
        bf16x8 o = (bf16x8)0;
        float s = 0.f;
        if (p < N_TOT) {
            const float* base = w + (size_t)p * C_IN + lane * 8;
            float4 a = *(const float4*)base;
            float4 c = *(const float4*)(base + 4);
            s = a.x*a.x + a.y*a.y + a.z*a.z + a.w*a.w
              + c.x*c.x + c.y*c.y + c.z*c.z + c.w*c.w;
            o[0] = (short)f2bf(a.x); o[1] = (short)f2bf(a.y);
            o[2] = (short)f2bf(a.z); o[3] = (short)f2bf(a.w);
            o[4] = (short)f2bf(c.x); o[5] = (short)f2bf(c.y);
            o[6] = (short)f2bf(c.z); o[7] = (short)f2bf(c.w);
        }
        *(bf16x8*)(Wbf + (size_t)p * C_IN + lane * 8) = o;
#pragma unroll
        for (int off = 32; off; off >>= 1) s += __shfl_down(s, off);
        if (lane == 0) w2[p] = s;
        return;
    }

    const int q = t & 15;
    const int part = t >> 4;
    const int m0q = blockIdx.x * 64 + q * 4;
    const uint32_t b  = (uint32_t)m0q / 784u;
    const uint32_t hw = (uint32_t)m0q % 784u;
    const float* base = in + (size_t)b * IMG_STRIDE + hw;

    float4 acc = make_float4(0.f, 0.f, 0.f, 0.f);
    const int c0 = part * 32;
#pragma unroll 4
    for (int c = c0; c < c0 + 32; ++c) {
        float4 v = *(const float4*)(base + (size_t)c * HW);
        acc.x = fmaf(v.x, v.x, acc.x);
        acc.y = fmaf(v.y, v.y, acc.y);
        acc.z = fmaf(v.z, v.z, acc.z);
        acc.w = fmaf(v.w, v.w, acc.w);
        uint16_t vals[4] = { f2bf(v.x), f2bf(v.y), f2bf(v.z), f2bf(v.w) };
        const uint32_t by0 = (uint32_t)(q * 4) * 1024u + (uint32_t)c * 2u;
#pragma unroll
        for (int j = 0; j < 4; ++j) {
            uint32_t bb = by0 + (uint32_t)j * 1024u;
            bb ^= ((bb >> 12) & 7u) << 4;
            *(uint16_t*)(T + bb) = vals[j];
        }
    }
    red[part][q * 4 + 0] = acc.x;
    red[part][q * 4 + 1] = acc.y;
    red[part][q * 4 + 2] = acc.z;
    red[part][q * 4 + 3] = acc.w;
    __syncthreads();
    if (t < 64) {
        float s = 0.f;
#pragma unroll
        for (int p = 0; p < 16; ++p) s += red[p][t];
        s2[blockIdx.x * 64 + t] = s;
    }
    short* dst = Abf + (size_t)blockIdx.x * 64 * 512;
#pragma unroll
    for (int i = 0; i < 16; ++i) {
        const int idx = i * 256 + t;
        const int row = idx >> 6, ch = idx & 63;
        uint32_t bb = (uint32_t)row * 1024u + (uint32_t)ch * 16u;
        bb ^= ((bb >> 12) & 7u) << 4;
        bf16x8 v = *(bf16x8*)(T + bb);
        *(bf16x8*)(dst + (size_t)row * 512 + ch * 8) = v;
    }
}

// ---------------------------------------------------------------------------
// gemm8: 256x128 tile, BK=64, ring-3 LDS (3 x 48 KB), 8 waves (4M x 2N),
// fine-grained 2-phase-per-K-tile schedule (m201-style): per phase
// {8 ds_read ∥ 3 gload_lds(T+2) -> barrier -> lgkmcnt(0) -> 16 MFMA -> barrier};
// end-of-tile vmcnt(6) gate BEFORE the collective barrier (counted, never 0
// mid-loop). Verified slot swizzle (slot s of row r holds k-group s^(r&7)).
//
// LDS buffer b (48 KB): A 256 rows x 128 B at +0, B 128 rows x 128 B at +32768.
__global__ __launch_bounds__(512, 2) void gemm8_kernel(const short* __restrict__ Abf,
                                                       const short* __restrict__ Wbf,
                                                       const float* __restrict__ s2,
                                                       const float* __restrict__ w2,
                                                       float* __restrict__ out) {
    __shared__ __align__(16) char smem[3 * 49152];   // 144 KB -> 1 block/CU

    const int t = threadIdx.x;
    const int wv = t >> 6, lane = t & 63;
    const int lr = lane & 15, lg = lane >> 4;

    const int bid = blockIdx.x;
    const int bn = bid & 15;     // bid%8 == bn%8 -> each XCD sees 2 B panels (L2-hot)
    const int bm = bid >> 4;     // 0..97

    const short* Ap = Abf + (size_t)bm * TBM * C_IN;
    const short* Bp = Wbf + (size_t)bn * TBN * C_IN;

    // ---- staging: load j dest byte = j*8192 + t*16 -> row = j*64 + wv*8 + (lane>>3),
    //      storage slot = lane&7. Source logical k-group = (lane&7)^((lane>>3)&7).
    const int srow = wv * 8 + (lane >> 3);
    const int sg   = (lane & 7) ^ ((lane >> 3) & 7);
    const short* AsrcL = Ap + (size_t)srow * C_IN + sg * 8;
    const short* BsrcL = Bp + (size_t)srow * C_IN + sg * 8;
    const int dst = t * 16;

    // ---- wave -> output subtile (64m x 64n): 4 M-groups x 2 N-groups
    const int wm = (wv >> 1) * 64;        // {0,64,128,192}
    const int wn = (wv & 1) * 64;         // {0,64}

    // ---- ds_read: row r, slot (kk*4+lg)^(r&7); r&7 == lr&7; kk=1 flips bit2 -> ^64
    const int s0    = (lg ^ (lr & 7)) * 16;
    const int arow0 = (wm + lr) * 128;
    const int brow0 = 32768 + (wn + lr) * 128;

    f32x4 acc[4][4] = {};

#define BATCH1(TT)                                                             \
    do {                                                                       \
        char* db = smem + ((TT) % 3) * 49152;                                  \
        const short* as_ = AsrcL + (TT) * 64;                                  \
        gload_lds16(as_,               db + dst);                              \
        gload_lds16(as_ +  64 * C_IN,  db + 8192 + dst);                       \
        gload_lds16(BsrcL + (TT) * 64, db + 32768 + dst);                      \
    } while (0)
#define BATCH2(TT)                                                             \
    do {                                                                       \
        char* db = smem + ((TT) % 3) * 49152;                                  \
        const short* as_ = AsrcL + (TT) * 64;                                  \
        gload_lds16(as_ + 128 * C_IN,  db + 16384 + dst);                      \
        gload_lds16(as_ + 192 * C_IN,  db + 24576 + dst);                      \
        gload_lds16(BsrcL + 64 * C_IN + (TT) * 64, db + 40960 + dst);          \
    } while (0)

    // prologue: stage tiles 0,1 (12 loads); gate vmcnt(6) = tile 0 landed,
    // tile 1's 6 stay in flight; collective barrier makes it true for all.
    BATCH1(0); BATCH2(0);
    BATCH1(1); BATCH2(1);
    asm volatile("s_waitcnt vmcnt(6)" ::: "memory");
    __builtin_amdgcn_sched_barrier(0);
    __builtin_amdgcn_s_barrier();
    __builtin_amdgcn_sched_barrier(0);

#pragma unroll
    for (int T = 0; T < NKT; ++T) {
        const char* buf = smem + (T % 3) * 49152;

        // ================= phase k0 =================
        {
            bf16x8 af[4], bfr[4];
#pragma unroll
            for (int m = 0; m < 4; ++m)
                af[m] = *(const bf16x8*)(buf + arow0 + m * 2048 + s0);
#pragma unroll
            for (int n = 0; n < 4; ++n)
                bfr[n] = *(const bf16x8*)(buf + brow0 + n * 2048 + s0);
            if (T + 2 < NKT) BATCH1(T + 2);   // buf (T+2)%3 == (T-1)%3: reads done last tile

            __builtin_amdgcn_sched_barrier(0);
            __builtin_amdgcn_s_barrier();
            asm volatile("s_waitcnt lgkmcnt(0)" ::: "memory");
            __builtin_amdgcn_sched_barrier(0);
            __builtin_amdgcn_s_setprio(1);
#pragma unroll
            for (int m = 0; m < 4; ++m)
#pragma unroll
                for (int n = 0; n < 4; ++n)
                    acc[m][n] = __builtin_amdgcn_mfma_f32_16x16x32_bf16(
                        af[m], bfr[n], acc[m][n], 0, 0, 0);
            __builtin_amdgcn_s_setprio(0);
            __builtin_amdgcn_sched_barrier(0);
            __builtin_amdgcn_s_barrier();
            __builtin_amdgcn_sched_barrier(0);
        }

        // ================= phase k1 =================
        {
            bf16x8 af[4], bfr[4];
#pragma unroll
            for (int m = 0; m < 4; ++m)
                af[m] = *(const bf16x8*)(buf + arow0 + m * 2048 + (s0 ^ 64));
#pragma unroll
            for (int n = 0; n < 4; ++n)
                bfr[n] = *(const bf16x8*)(buf + brow0 + n * 2048 + (s0 ^ 64));
            if (T + 2 < NKT) BATCH2(T + 2);

            __builtin_amdgcn_sched_barrier(0);
            __builtin_amdgcn_s_barrier();
            asm volatile("s_waitcnt lgkmcnt(0)" ::: "memory");
            __builtin_amdgcn_sched_barrier(0);
            __builtin_amdgcn_s_setprio(1);
#pragma unroll
            for (int m = 0; m < 4; ++m)
#pragma unroll
                for (int n = 0; n < 4; ++n)
                    acc[m][n] = __builtin_amdgcn_mfma_f32_16x16x32_bf16(
                        af[m], bfr[n], acc[m][n], 0, 0, 0);
            __builtin_amdgcn_s_setprio(0);

            // end-of-tile gate: own stage(T+1) landed (leave stage(T+2)'s 6
            // in flight), then COLLECTIVE barrier -> everyone's landed.
            if (T < NKT - 2)       asm volatile("s_waitcnt vmcnt(6)" ::: "memory");
            else if (T == NKT - 2) asm volatile("s_waitcnt vmcnt(0)" ::: "memory");
            __builtin_amdgcn_sched_barrier(0);
            if (T < NKT - 1) {
                __builtin_amdgcn_s_barrier();
                __builtin_amdgcn_sched_barrier(0);
            }
        }
    }
#undef BATCH1
#undef BATCH2

    // epilogue: relu(s2 - 2*acc + w2), float4 over 4 consecutive m (hw-contig)
#pragma unroll
    for (int m = 0; m < 4; ++m) {
        const int m_r = bm * TBM + wm + m * 16 + lg * 4;   // 4-aligned, 784%4==0
        const float4 s2v = *(const float4*)(s2 + m_r);
        const uint32_t ob  = (uint32_t)m_r / 784u;
        const uint32_t ohw = (uint32_t)m_r % 784u;
        float* obase = out + (size_t)ob * OUT_BATCH + ohw;
#pragma unroll
        for (int n = 0; n < 4; ++n) {
            const int n_o = bn * TBN + wn + n * 16 + lr;
            if (n_o < N_TOT) {
                const float wvv = w2[n_o];
                const f32x4 a = acc[m][n];
                float4 r;
                r.x = fmaxf(s2v.x - 2.f * a.x + wvv, 0.f);
                r.y = fmaxf(s2v.y - 2.f * a.y + wvv, 0.f);
                r.z = fmaxf(s2v.z - 2.f * a.z + wvv, 0.f);
                r.w = fmaxf(s2v.w - 2.f * a.w + wvv, 0.f);
                *(float4*)(obase + (size_t)n_o * HW) = r;
            }
        }
    }
}

// ---------------------------------------------------------------------------
extern "C" void kernel_launch(void* const* d_in, const int* in_sizes, int n_in,
                              void* d_out, int out_size, void* d_ws, size_t ws_size,
                              hipStream_t stream) {
    const float* in = (const float*)d_in[0];   // [32,512,28,28] fp32
    const float* w  = (const float*)d_in[1];   // [2000,512,1,1] fp32
    float* out = (float*)d_out;                // [32,2000,28,28] fp32

    const size_t offA  = 0;
    const size_t offW  = offA + (size_t)M_TOT * C_IN * sizeof(short);   // 25.7 MB
    const size_t offS2 = offW + (size_t)NPAD * C_IN * sizeof(short);    // +2.1 MB
    const size_t offW2 = offS2 + (size_t)M_TOT * sizeof(float);

    short* Abf = (short*)((char*)d_ws + offA);
    short* Wbf = (short*)((char*)d_ws + offW);
    float* s2  = (float*)((char*)d_ws + offS2);
    float* w2  = (float*)((char*)d_ws + offW2);

    prep_kernel<<<PREPA_BLOCKS + PREPW_BLOCKS, 256, 0, stream>>>(in, w, Abf, Wbf, s2, w2);

    // 98 m-tiles x 16 n-tiles = 1568 blocks, 1 per CU (6.125 rounds: small tail)
    gemm8_kernel<<<98 * 16, 512, 0, stream>>>(Abf, Wbf, s2, w2, out);
}

// Round 9
// 104.765 us; speedup vs baseline: 2.4614x; 1.1756x over previous
//
#include <hip/hip_runtime.h>
#include <stdint.h>

// Problem constants
constexpr int C_IN  = 512;
constexpr int HW    = 784;            // 28*28
constexpr int NB    = 32;
constexpr int M_TOT = NB * HW;        // 25088 = 98*256
constexpr int N_TOT = 2000;
constexpr int NPAD  = 2048;
constexpr int IMG_STRIDE = C_IN * HW;
constexpr int OUT_BATCH  = N_TOT * HW;

// GEMM tiling: 256x128 block, 4 waves (wave 128x64), BK=32, ring-3, 2 blk/CU
constexpr int TBM = 256;
constexpr int TBN = 128;
constexpr int NKT = C_IN / 32;        // 16

constexpr int PREPA_BLOCKS = M_TOT / 64;   // 392
constexpr int PREPW_BLOCKS = NPAD / 4;     // 512

typedef __attribute__((ext_vector_type(8))) short bf16x8;
typedef __attribute__((ext_vector_type(4))) float f32x4;

__device__ __forceinline__ uint16_t f2bf(float f) {
    union { float f; uint32_t u; } x; x.f = f;
    return (uint16_t)((x.u + 0x8000u) >> 16);
}

__device__ __forceinline__ void gload_lds16(const void* g, void* l) {
    __builtin_amdgcn_global_load_lds(
        (const __attribute__((address_space(1))) void*)g,
        (__attribute__((address_space(3))) void*)l, 16, 0, 0);
}

// ---------------------------------------------------------------------------
// prep: blocks [0,392): Abf[m][k] = bf16(input) transposed via LDS, fused s2[m]
//       blocks [392,904): Wbf[p][k] = bf16(w) (rows >= N_TOT zeroed), fused w2[p]
__global__ __launch_bounds__(256) void prep_kernel(const float* __restrict__ in,
                                                   const float* __restrict__ w,
                                                   short* __restrict__ Abf,
                                                   short* __restrict__ Wbf,
                                                   float* __restrict__ s2,
                                                   float* __restrict__ w2) {
    __shared__ __align__(16) char T[64 * 512 * 2];
    __shared__ float red[16][64];

    const int t = threadIdx.x;

    if (blockIdx.x >= PREPA_BLOCKS) {
        const int wv = t >> 6, lane = t & 63;
        const int p = (blockIdx.x - PREPA_BLOCKS) * 4 + wv;
        bf16x8 o = (bf16x8)0;
        float s = 0.f;
        if (p < N_TOT) {
            const float* base = w + (size_t)p * C_IN + lane * 8;
            float4 a = *(const float4*)base;
            float4 c = *(const float4*)(base + 4);
            s = a.x*a.x + a.y*a.y + a.z*a.z + a.w*a.w
              + c.x*c.x + c.y*c.y + c.z*c.z + c.w*c.w;
            o[0] = (short)f2bf(a.x); o[1] = (short)f2bf(a.y);
            o[2] = (short)f2bf(a.z); o[3] = (short)f2bf(a.w);
            o[4] = (short)f2bf(c.x); o[5] = (short)f2bf(c.y);
            o[6] = (short)f2bf(c.z); o[7] = (short)f2bf(c.w);
        }
        *(bf16x8*)(Wbf + (size_t)p * C_IN + lane * 8) = o;
#pragma unroll
        for (int off = 32; off; off >>= 1) s += __shfl_down(s, off);
        if (lane == 0) w2[p] = s;
        return;
    }

    const int q = t & 15;
    const int part = t >> 4;
    const int m0q = blockIdx.x * 64 + q * 4;
    const uint32_t b  = (uint32_t)m0q / 784u;
    const uint32_t hw = (uint32_t)m0q % 784u;
    const float* base = in + (size_t)b * IMG_STRIDE + hw;

    float4 acc = make_float4(0.f, 0.f, 0.f, 0.f);
    const int c0 = part * 32;
#pragma unroll 4
    for (int c = c0; c < c0 + 32; ++c) {
        float4 v = *(const float4*)(base + (size_t)c * HW);
        acc.x = fmaf(v.x, v.x, acc.x);
        acc.y = fmaf(v.y, v.y, acc.y);
        acc.z = fmaf(v.z, v.z, acc.z);
        acc.w = fmaf(v.w, v.w, acc.w);
        uint16_t vals[4] = { f2bf(v.x), f2bf(v.y), f2bf(v.z), f2bf(v.w) };
        const uint32_t by0 = (uint32_t)(q * 4) * 1024u + (uint32_t)c * 2u;
#pragma unroll
        for (int j = 0; j < 4; ++j) {
            uint32_t bb = by0 + (uint32_t)j * 1024u;
            bb ^= ((bb >> 12) & 7u) << 4;
            *(uint16_t*)(T + bb) = vals[j];
        }
    }
    red[part][q * 4 + 0] = acc.x;
    red[part][q * 4 + 1] = acc.y;
    red[part][q * 4 + 2] = acc.z;
    red[part][q * 4 + 3] = acc.w;
    __syncthreads();
    if (t < 64) {
        float s = 0.f;
#pragma unroll
        for (int p = 0; p < 16; ++p) s += red[p][t];
        s2[blockIdx.x * 64 + t] = s;
    }
    short* dst = Abf + (size_t)blockIdx.x * 64 * 512;
#pragma unroll
    for (int i = 0; i < 16; ++i) {
        const int idx = i * 256 + t;
        const int row = idx >> 6, ch = idx & 63;
        uint32_t bb = (uint32_t)row * 1024u + (uint32_t)ch * 16u;
        bb ^= ((bb >> 12) & 7u) << 4;
        bf16x8 v = *(bf16x8*)(T + bb);
        *(bf16x8*)(dst + (size_t)row * 512 + ch * 8) = v;
    }
}

// ---------------------------------------------------------------------------
// gemm9: 256x128 block, 4 waves (wave owns 128m x 64n, acc[8][4]), BK=32,
// ring-3 LDS (3 x 24 KB = 72 KB -> 2 blocks/CU), single barrier per K-tile,
// counted vmcnt gate (6 = next tile's loads stay in flight; 0 only at last),
// measured-0-conflict slot swizzle (storage slot s of row r holds logical
// k-group s ^ ((r>>1)&3); linear LDS dest, pre-swizzled global source).
//
// LDS buffer (24 KB): A 256 rows x 64 B at +0, B 128 rows x 64 B at +16384.
__global__ __launch_bounds__(256, 2) void gemm9_kernel(const short* __restrict__ Abf,
                                                       const short* __restrict__ Wbf,
                                                       const float* __restrict__ s2,
                                                       const float* __restrict__ w2,
                                                       float* __restrict__ out) {
    __shared__ __align__(16) char smem[3 * 24576];   // 72 KB

    const int t = threadIdx.x;
    const int wv = t >> 6, lane = t & 63;
    const int lr = lane & 15, lg = lane >> 4;

    const int bid = blockIdx.x;
    const int bn = bid & 15;     // fast: 16 consecutive blocks share one A panel;
    const int bm = bid >> 4;     // XCD x (bid%8) sees bn in {x, x+8} -> B L2-hot

    const short* Ap = Abf + (size_t)bm * TBM * C_IN;
    const short* Bp = Wbf + (size_t)bn * TBN * C_IN;

    // ---- staging: instr j dest = buf + jbase + t*16
    //      -> row = jrow + wv*16 + (lane>>2), storage slot = lane&3
    //      source logical k-group = (lane&3) ^ ((row>>1)&3) = (lane&3)^((lane>>3)&3)
    const int srow = wv * 16 + (lane >> 2);
    const int sg   = (lane & 3) ^ ((lane >> 3) & 3);
    const short* AsrcL = Ap + (size_t)srow * C_IN + sg * 8;   // + j*64 rows
    const short* BsrcL = Bp + (size_t)srow * C_IN + sg * 8;   // + j*64 rows
    const int dst = t * 16;

    // ---- wave -> output subtile (128m x 64n)
    const int wm = (wv >> 1) * 128;        // {0,128}
    const int wn = (wv & 1) * 64;          // {0,64}

    // ---- ds_read: row r at 64 B stride, slot lg^((lr>>1)&3)
    const int slot  = lg ^ ((lr >> 1) & 3);
    const int abase = (wm + lr) * 64 + slot * 16;            // + m*1024
    const int bbase = 16384 + (wn + lr) * 64 + slot * 16;    // + n*1024

    f32x4 acc[8][4] = {};

#define STAGE(tt)                                                              \
    do {                                                                       \
        char* buf_ = smem + ((tt) % 3) * 24576;                                \
        const short* as_ = AsrcL + (tt) * 32;                                  \
        const short* bs_ = BsrcL + (tt) * 32;                                  \
        gload_lds16(as_,              buf_ + dst);                             \
        gload_lds16(as_ +  64 * C_IN, buf_ + 4096 + dst);                      \
        gload_lds16(as_ + 128 * C_IN, buf_ + 8192 + dst);                      \
        gload_lds16(as_ + 192 * C_IN, buf_ + 12288 + dst);                     \
        gload_lds16(bs_,              buf_ + 16384 + dst);                     \
        gload_lds16(bs_ +  64 * C_IN, buf_ + 20480 + dst);                     \
    } while (0)

    // prologue: issue stages for tiles 0,1 (12 loads in flight)
    STAGE(0);
    STAGE(1);

#pragma unroll
    for (int kt = 0; kt < NKT; ++kt) {
        // entry gate: my stage(kt) landed; stage(kt+1)'s 6 stay in flight
        if (kt < NKT - 1) asm volatile("s_waitcnt vmcnt(6)" ::: "memory");
        else              asm volatile("s_waitcnt vmcnt(0)" ::: "memory");
        __builtin_amdgcn_sched_barrier(0);
        __builtin_amdgcn_s_barrier();      // all waves' stage(kt) landed;
        __builtin_amdgcn_sched_barrier(0); // buf (kt+2)%3 fully consumed (iter kt-1)

        if (kt + 2 < NKT) STAGE(kt + 2);   // into buffer freed at this barrier

        const char* buf = smem + (kt % 3) * 24576;
        bf16x8 bfrag[4], afrag[8];
#pragma unroll
        for (int n = 0; n < 4; ++n)
            bfrag[n] = *(const bf16x8*)(buf + bbase + n * 1024);
#pragma unroll
        for (int m = 0; m < 8; ++m)
            afrag[m] = *(const bf16x8*)(buf + abase + m * 1024);

        __builtin_amdgcn_s_setprio(1);
#pragma unroll
        for (int m = 0; m < 8; ++m)
#pragma unroll
            for (int n = 0; n < 4; ++n)
                acc[m][n] = __builtin_amdgcn_mfma_f32_16x16x32_bf16(
                    afrag[m], bfrag[n], acc[m][n], 0, 0, 0);
        __builtin_amdgcn_s_setprio(0);
    }
#undef STAGE

    // epilogue: relu(s2 - 2*acc + w2), float4 over 4 consecutive m (hw-contig)
    float wreg[4];
    int n_ok[4];
#pragma unroll
    for (int n = 0; n < 4; ++n) {
        const int n_o = bn * TBN + wn + n * 16 + lr;
        n_ok[n] = (n_o < N_TOT);
        wreg[n] = n_ok[n] ? w2[n_o] : 0.f;
    }
#pragma unroll
    for (int m = 0; m < 8; ++m) {
        const int m_r = bm * TBM + wm + m * 16 + lg * 4;   // 4-aligned, 784%4==0
        const float4 s2v = *(const float4*)(s2 + m_r);
        const uint32_t ob  = (uint32_t)m_r / 784u;
        const uint32_t ohw = (uint32_t)m_r % 784u;
        float* obase = out + (size_t)ob * OUT_BATCH + ohw;
#pragma unroll
        for (int n = 0; n < 4; ++n) {
            if (n_ok[n]) {
                const int n_o = bn * TBN + wn + n * 16 + lr;
                const f32x4 a = acc[m][n];
                float4 r;
                r.x = fmaxf(s2v.x - 2.f * a.x + wreg[n], 0.f);
                r.y = fmaxf(s2v.y - 2.f * a.y + wreg[n], 0.f);
                r.z = fmaxf(s2v.z - 2.f * a.z + wreg[n], 0.f);
                r.w = fmaxf(s2v.w - 2.f * a.w + wreg[n], 0.f);
                *(float4*)(obase + (size_t)n_o * HW) = r;
            }
        }
    }
}

// ---------------------------------------------------------------------------
extern "C" void kernel_launch(void* const* d_in, const int* in_sizes, int n_in,
                              void* d_out, int out_size, void* d_ws, size_t ws_size,
                              hipStream_t stream) {
    const float* in = (const float*)d_in[0];   // [32,512,28,28] fp32
    const float* w  = (const float*)d_in[1];   // [2000,512,1,1] fp32
    float* out = (float*)d_out;                // [32,2000,28,28] fp32

    const size_t offA  = 0;
    const size_t offW  = offA + (size_t)M_TOT * C_IN * sizeof(short);   // 25.7 MB
    const size_t offS2 = offW + (size_t)NPAD * C_IN * sizeof(short);    // +2.1 MB
    const size_t offW2 = offS2 + (size_t)M_TOT * sizeof(float);

    short* Abf = (short*)((char*)d_ws + offA);
    short* Wbf = (short*)((char*)d_ws + offW);
    float* s2  = (float*)((char*)d_ws + offS2);
    float* w2  = (float*)((char*)d_ws + offW2);

    prep_kernel<<<PREPA_BLOCKS + PREPW_BLOCKS, 256, 0, stream>>>(in, w, Abf, Wbf, s2, w2);

    // 98 m-tiles x 16 n-tiles = 1568 blocks, 2 resident per CU (3.06 rounds)
    gemm9_kernel<<<98 * 16, 256, 0, stream>>>(Abf, Wbf, s2, w2, out);
}

// Round 11
// 103.962 us; speedup vs baseline: 2.4804x; 1.0077x over previous
//
#include <hip/hip_runtime.h>
#include <stdint.h>

// Problem constants
constexpr int C_IN  = 512;
constexpr int HW    = 784;            // 28*28
constexpr int NB    = 32;
constexpr int M_TOT = NB * HW;        // 25088 = 98*256
constexpr int N_TOT = 2000;
constexpr int NPAD  = 2048;
constexpr int IMG_STRIDE = C_IN * HW;
constexpr int OUT_BATCH  = N_TOT * HW;

// GEMM tiling: 256x128 block, 4 waves (wave 128x64), BK=32, ring-3, 2 blk/CU
constexpr int TBM = 256;
constexpr int TBN = 128;
constexpr int NKT = C_IN / 32;        // 16

constexpr int PREPA_BLOCKS = M_TOT / 64;   // 392
constexpr int PREPW_BLOCKS = NPAD / 4;     // 512

typedef __attribute__((ext_vector_type(8))) short bf16x8;
typedef __attribute__((ext_vector_type(4))) float f32x4;

__device__ __forceinline__ uint16_t f2bf(float f) {
    union { float f; uint32_t u; } x; x.f = f;
    return (uint16_t)((x.u + 0x8000u) >> 16);
}

__device__ __forceinline__ void gload_lds16(const void* g, void* l) {
    __builtin_amdgcn_global_load_lds(
        (const __attribute__((address_space(1))) void*)g,
        (__attribute__((address_space(3))) void*)l, 16, 0, 0);
}

// non-temporal 16B load/store via clang ext_vector (HIP float4 is rejected)
__device__ __forceinline__ f32x4 nt_load4(const float* p) {
    return __builtin_nontemporal_load((const f32x4*)p);
}
__device__ __forceinline__ void nt_store4(float* p, f32x4 v) {
    __builtin_nontemporal_store(v, (f32x4*)p);
}

// ---------------------------------------------------------------------------
// prep: blocks [0,392): Abf[m][k] = bf16(input) transposed via LDS, fused s2[m]
//       blocks [392,904): Wbf[p][k] = bf16(w) (rows >= N_TOT zeroed), fused w2[p]
// Input is read exactly once -> non-temporal loads (keep L3 for Abf/Wbf).
__global__ __launch_bounds__(256) void prep_kernel(const float* __restrict__ in,
                                                   const float* __restrict__ w,
                                                   short* __restrict__ Abf,
                                                   short* __restrict__ Wbf,
                                                   float* __restrict__ s2,
                                                   float* __restrict__ w2) {
    __shared__ __align__(16) char T[64 * 512 * 2];
    __shared__ float red[16][64];

    const int t = threadIdx.x;

    if (blockIdx.x >= PREPA_BLOCKS) {
        const int wv = t >> 6, lane = t & 63;
        const int p = (blockIdx.x - PREPA_BLOCKS) * 4 + wv;
        bf16x8 o = (bf16x8)0;
        float s = 0.f;
        if (p < N_TOT) {
            const float* base = w + (size_t)p * C_IN + lane * 8;
            f32x4 a = nt_load4(base);
            f32x4 c = nt_load4(base + 4);
            s = a[0]*a[0] + a[1]*a[1] + a[2]*a[2] + a[3]*a[3]
              + c[0]*c[0] + c[1]*c[1] + c[2]*c[2] + c[3]*c[3];
            o[0] = (short)f2bf(a[0]); o[1] = (short)f2bf(a[1]);
            o[2] = (short)f2bf(a[2]); o[3] = (short)f2bf(a[3]);
            o[4] = (short)f2bf(c[0]); o[5] = (short)f2bf(c[1]);
            o[6] = (short)f2bf(c[2]); o[7] = (short)f2bf(c[3]);
        }
        *(bf16x8*)(Wbf + (size_t)p * C_IN + lane * 8) = o;
#pragma unroll
        for (int off = 32; off; off >>= 1) s += __shfl_down(s, off);
        if (lane == 0) w2[p] = s;
        return;
    }

    const int q = t & 15;
    const int part = t >> 4;
    const int m0q = blockIdx.x * 64 + q * 4;
    const uint32_t b  = (uint32_t)m0q / 784u;
    const uint32_t hw = (uint32_t)m0q % 784u;
    const float* base = in + (size_t)b * IMG_STRIDE + hw;

    float acx = 0.f, acy = 0.f, acz = 0.f, acw = 0.f;
    const int c0 = part * 32;
#pragma unroll 4
    for (int c = c0; c < c0 + 32; ++c) {
        f32x4 v = nt_load4(base + (size_t)c * HW);
        acx = fmaf(v[0], v[0], acx);
        acy = fmaf(v[1], v[1], acy);
        acz = fmaf(v[2], v[2], acz);
        acw = fmaf(v[3], v[3], acw);
        uint16_t vals[4] = { f2bf(v[0]), f2bf(v[1]), f2bf(v[2]), f2bf(v[3]) };
        const uint32_t by0 = (uint32_t)(q * 4) * 1024u + (uint32_t)c * 2u;
#pragma unroll
        for (int j = 0; j < 4; ++j) {
            uint32_t bb = by0 + (uint32_t)j * 1024u;
            bb ^= ((bb >> 12) & 7u) << 4;
            *(uint16_t*)(T + bb) = vals[j];
        }
    }
    red[part][q * 4 + 0] = acx;
    red[part][q * 4 + 1] = acy;
    red[part][q * 4 + 2] = acz;
    red[part][q * 4 + 3] = acw;
    __syncthreads();
    if (t < 64) {
        float s = 0.f;
#pragma unroll
        for (int p = 0; p < 16; ++p) s += red[p][t];
        s2[blockIdx.x * 64 + t] = s;
    }
    short* dst = Abf + (size_t)blockIdx.x * 64 * 512;
#pragma unroll
    for (int i = 0; i < 16; ++i) {
        const int idx = i * 256 + t;
        const int row = idx >> 6, ch = idx & 63;
        uint32_t bb = (uint32_t)row * 1024u + (uint32_t)ch * 16u;
        bb ^= ((bb >> 12) & 7u) << 4;
        bf16x8 v = *(bf16x8*)(T + bb);
        *(bf16x8*)(dst + (size_t)row * 512 + ch * 8) = v;
    }
}

// ---------------------------------------------------------------------------
// gemm10: gemm9 loop (256x128 block, 4 waves of 128x64, BK=32, ring-3 LDS
// 72 KB -> 2 blocks/CU, single barrier + counted vmcnt(6) per K-tile,
// measured-0-conflict slot swizzle) + NON-TEMPORAL output stores so the
// 200 MB write stream bypasses L3 and A/B panels (28 MB) stay L3-resident.
__global__ __launch_bounds__(256, 2) void gemm10_kernel(const short* __restrict__ Abf,
                                                        const short* __restrict__ Wbf,
                                                        const float* __restrict__ s2,
                                                        const float* __restrict__ w2,
                                                        float* __restrict__ out) {
    __shared__ __align__(16) char smem[3 * 24576];   // 72 KB

    const int t = threadIdx.x;
    const int wv = t >> 6, lane = t & 63;
    const int lr = lane & 15, lg = lane >> 4;

    const int bid = blockIdx.x;
    const int bn = bid & 15;     // fast: 16 consecutive blocks share one A panel
    const int bm = bid >> 4;

    const short* Ap = Abf + (size_t)bm * TBM * C_IN;
    const short* Bp = Wbf + (size_t)bn * TBN * C_IN;

    // ---- staging: instr j dest = buf + jbase + t*16
    //      -> row = jrow + wv*16 + (lane>>2), storage slot = lane&3
    //      source logical k-group = (lane&3) ^ ((row>>1)&3) = (lane&3)^((lane>>3)&3)
    const int srow = wv * 16 + (lane >> 2);
    const int sg   = (lane & 3) ^ ((lane >> 3) & 3);
    const short* AsrcL = Ap + (size_t)srow * C_IN + sg * 8;   // + j*64 rows
    const short* BsrcL = Bp + (size_t)srow * C_IN + sg * 8;   // + j*64 rows
    const int dst = t * 16;

    // ---- wave -> output subtile (128m x 64n)
    const int wm = (wv >> 1) * 128;        // {0,128}
    const int wn = (wv & 1) * 64;          // {0,64}

    // ---- ds_read: row r at 64 B stride, slot lg^((lr>>1)&3)
    const int slot  = lg ^ ((lr >> 1) & 3);
    const int abase = (wm + lr) * 64 + slot * 16;            // + m*1024
    const int bbase = 16384 + (wn + lr) * 64 + slot * 16;    // + n*1024

    f32x4 acc[8][4] = {};

#define STAGE(tt)                                                              \
    do {                                                                       \
        char* buf_ = smem + ((tt) % 3) * 24576;                                \
        const short* as_ = AsrcL + (tt) * 32;                                  \
        const short* bs_ = BsrcL + (tt) * 32;                                  \
        gload_lds16(as_,              buf_ + dst);                             \
        gload_lds16(as_ +  64 * C_IN, buf_ + 4096 + dst);                      \
        gload_lds16(as_ + 128 * C_IN, buf_ + 8192 + dst);                      \
        gload_lds16(as_ + 192 * C_IN, buf_ + 12288 + dst);                     \
        gload_lds16(bs_,              buf_ + 16384 + dst);                     \
        gload_lds16(bs_ +  64 * C_IN, buf_ + 20480 + dst);                     \
    } while (0)

    // prologue: issue stages for tiles 0,1 (12 loads in flight)
    STAGE(0);
    STAGE(1);

#pragma unroll
    for (int kt = 0; kt < NKT; ++kt) {
        // entry gate: my stage(kt) landed; stage(kt+1)'s 6 stay in flight
        if (kt < NKT - 1) asm volatile("s_waitcnt vmcnt(6)" ::: "memory");
        else              asm volatile("s_waitcnt vmcnt(0)" ::: "memory");
        __builtin_amdgcn_sched_barrier(0);
        __builtin_amdgcn_s_barrier();      // all waves' stage(kt) landed;
        __builtin_amdgcn_sched_barrier(0); // buf (kt+2)%3 fully consumed (iter kt-1)

        if (kt + 2 < NKT) STAGE(kt + 2);   // into buffer freed at this barrier

        const char* buf = smem + (kt % 3) * 24576;
        bf16x8 bfrag[4], afrag[8];
#pragma unroll
        for (int n = 0; n < 4; ++n)
            bfrag[n] = *(const bf16x8*)(buf + bbase + n * 1024);
#pragma unroll
        for (int m = 0; m < 8; ++m)
            afrag[m] = *(const bf16x8*)(buf + abase + m * 1024);

        __builtin_amdgcn_s_setprio(1);
#pragma unroll
        for (int m = 0; m < 8; ++m)
#pragma unroll
            for (int n = 0; n < 4; ++n)
                acc[m][n] = __builtin_amdgcn_mfma_f32_16x16x32_bf16(
                    afrag[m], bfrag[n], acc[m][n], 0, 0, 0);
        __builtin_amdgcn_s_setprio(0);
    }
#undef STAGE

    // epilogue: relu(s2 - 2*acc + w2), non-temporal f32x4 stores (bypass L3)
    float wreg[4];
    int n_ok[4];
#pragma unroll
    for (int n = 0; n < 4; ++n) {
        const int n_o = bn * TBN + wn + n * 16 + lr;
        n_ok[n] = (n_o < N_TOT);
        wreg[n] = n_ok[n] ? w2[n_o] : 0.f;
    }
#pragma unroll
    for (int m = 0; m < 8; ++m) {
        const int m_r = bm * TBM + wm + m * 16 + lg * 4;   // 4-aligned, 784%4==0
        const f32x4 s2v = *(const f32x4*)(s2 + m_r);
        const uint32_t ob  = (uint32_t)m_r / 784u;
        const uint32_t ohw = (uint32_t)m_r % 784u;
        float* obase = out + (size_t)ob * OUT_BATCH + ohw;
#pragma unroll
        for (int n = 0; n < 4; ++n) {
            if (n_ok[n]) {
                const int n_o = bn * TBN + wn + n * 16 + lr;
                const f32x4 a = acc[m][n];
                f32x4 r;
                r[0] = fmaxf(s2v[0] - 2.f * a[0] + wreg[n], 0.f);
                r[1] = fmaxf(s2v[1] - 2.f * a[1] + wreg[n], 0.f);
                r[2] = fmaxf(s2v[2] - 2.f * a[2] + wreg[n], 0.f);
                r[3] = fmaxf(s2v[3] - 2.f * a[3] + wreg[n], 0.f);
                nt_store4(obase + (size_t)n_o * HW, r);
            }
        }
    }
}

// ---------------------------------------------------------------------------
extern "C" void kernel_launch(void* const* d_in, const int* in_sizes, int n_in,
                              void* d_out, int out_size, void* d_ws, size_t ws_size,
                              hipStream_t stream) {
    const float* in = (const float*)d_in[0];   // [32,512,28,28] fp32
    const float* w  = (const float*)d_in[1];   // [2000,512,1,1] fp32
    float* out = (float*)d_out;                // [32,2000,28,28] fp32

    const size_t offA  = 0;
    const size_t offW  = offA + (size_t)M_TOT * C_IN * sizeof(short);   // 25.7 MB
    const size_t offS2 = offW + (size_t)NPAD * C_IN * sizeof(short);    // +2.1 MB
    const size_t offW2 = offS2 + (size_t)M_TOT * sizeof(float);

    short* Abf = (short*)((char*)d_ws + offA);
    short* Wbf = (short*)((char*)d_ws + offW);
    float* s2  = (float*)((char*)d_ws + offS2);
    float* w2  = (float*)((char*)d_ws + offW2);

    prep_kernel<<<PREPA_BLOCKS + PREPW_BLOCKS, 256, 0, stream>>>(in, w, Abf, Wbf, s2, w2);

    // 98 m-tiles x 16 n-tiles = 1568 blocks, 2 resident per CU (3.06 rounds)
    gemm10_kernel<<<98 * 16, 256, 0, stream>>>(Abf, Wbf, s2, w2, out);
}